// Round 5
// baseline (190.388 us; speedup 1.0000x reference)
//
#include <hip/hip_runtime.h>
#include <hip/hip_bf16.h>
#include <stdint.h>

// Swin-3D window attention, fused. B=4096 windows, N=64 tokens, C=96, H=8, hd=12.
// R5: LDS cut to 50 KB -> 3 blocks/CU (6 waves/SIMD). X loaded per-wave from
// global (no staging buffer/barrier); q_s/k_s [8][64][16]; O overlays v_s.
// 512 thr / 8 waves, one head per wave.
//
// ws layout (bytes):
//   [0, 8388608)            biasm fp32 [64 w][8 h][64 q][64 m]  ((bias+mask)*log2e)
//   [8388608, +55296)       wqkv  bf16 [288][96]  (Q rows pre-scaled by hd^-0.5*log2e)
//   [8443904, +18432)       wproj bf16 [96][96]

typedef float  f32x4  __attribute__((ext_vector_type(4)));
typedef float  f32x16 __attribute__((ext_vector_type(16)));
typedef short  short8 __attribute__((ext_vector_type(8)));

#define WS_WQKV_OFF  (8388608)
#define WS_WPROJ_OFF (8388608 + 55296)
#define LOG2E 1.4426950408889634f

__device__ __forceinline__ unsigned short f2bf(float f) {
  __hip_bfloat16 h = __float2bfloat16(f);
  return *reinterpret_cast<unsigned short*>(&h);
}
__device__ __forceinline__ uint32_t pack2(float a, float b) {
  __hip_bfloat162 h = __float22bfloat162_rn(float2{a, b});
  return *reinterpret_cast<uint32_t*>(&h);
}

__global__ void prep_weights(const float* __restrict__ qkv_w,
                             const float* __restrict__ proj_w,
                             unsigned short* __restrict__ ws16) {
  int tid = blockIdx.x * 256 + threadIdx.x;          // 144 blocks * 256 = 36864 exact
  if (tid < 27648) {
    float v = qkv_w[tid];
    if (tid < 9216) v *= (0.28867513459481288f * LOG2E);  // SCALE*log2e into Q rows
    ws16[WS_WQKV_OFF / 2 + tid] = f2bf(v);
  } else {
    int t = tid - 27648;                             // < 9216
    ws16[WS_WPROJ_OFF / 2 + t] = f2bf(proj_w[t]);
  }
}

// biasm[w][h][q=r][key=m] = (bias_table[relidx(r,m)][h] + mask[w][r][m]) * log2e
__global__ void prep_biasm(const float* __restrict__ mask,
                           const float* __restrict__ bias_table,
                           float* __restrict__ biasm) {
  int tid = blockIdx.x * 256 + threadIdx.x;          // 8192 blocks * 256 = 2097152 exact
  int m = tid & 63;            // key (inner)
  int r = (tid >> 6) & 63;     // query
  int h = (tid >> 12) & 7;
  int w = tid >> 15;
  int dr = r >> 4, hr = (r >> 2) & 3, wr = r & 3;
  int dm = m >> 4, hm = (m >> 2) & 3, wm = m & 3;
  int idx = (dr - dm + 3) * 49 + (hr - hm + 3) * 7 + (wr - wm + 3);
  biasm[tid] = (bias_table[idx * 8 + h] + mask[(w * 64 + r) * 64 + m]) * LOG2E;
}

__global__ __launch_bounds__(512, 6) void attn_main(
    const float* __restrict__ x, const float* __restrict__ proj_b,
    const unsigned short* __restrict__ ws16, const float* __restrict__ biasm,
    float* __restrict__ out) {
  // 51200 B total LDS -> 3 blocks/CU
  __shared__ __align__(16) unsigned short q_s[8][64][16];  // token-major, chans 12..15 zero
  __shared__ __align__(16) unsigned short k_s[8][64][16];
  __shared__ __align__(16) unsigned short v_s[8][16][72];  // chan-major; O overlays later

  const int tid  = threadIdx.x;
  const int wv   = tid >> 6;          // 0..7
  const int lane = tid & 63;
  const int lo4 = lane & 15, hi4 = lane >> 4;
  const int lo5 = lane & 31, hi5 = lane >> 5;
  const int blk = blockIdx.x;
  const int wmask = blk & 63;

  const unsigned short* wqkv  = ws16 + WS_WQKV_OFF / 2;
  const unsigned short* wproj = ws16 + WS_WPROJ_OFF / 2;
  unsigned short (*o_s)[104] = reinterpret_cast<unsigned short(*)[104]>(&v_s[0][0][0]);

  // --- zero pad chans 12..15 of q_s/k_s (512 threads -> one shot) ---
  {
    int h = tid >> 6, r = tid & 63;
    *(uint2*)&q_s[h][r][12] = make_uint2(0u, 0u);
    *(uint2*)&k_s[h][r][12] = make_uint2(0u, 0u);
  }

  // --- GEMM1 (transposed): QKV^T = Wqkv @ X^T. B-frags of X loaded directly
  //     from global (L1-resident 24 KB block). wave = (token-tile sub, parity) ---
  {
    const int sub = wv & 3;           // token tile (16 tokens)
    const int par = wv >> 2;          // M-tile parity
    const int trow = sub * 16 + lo4;  // this lane's token
    const float* xrow = x + (size_t)blk * 6144 + (size_t)trow * 96;
    float4 xa[6];
#pragma unroll
    for (int ks = 0; ks < 3; ++ks) {
      xa[2 * ks]     = *(const float4*)&xrow[ks * 32 + hi4 * 8];
      xa[2 * ks + 1] = *(const float4*)&xrow[ks * 32 + hi4 * 8 + 4];
    }
    short8 bfX[3];
#pragma unroll
    for (int ks = 0; ks < 3; ++ks) {
      union { uint32_t u[4]; short8 s; } t;
      t.u[0] = pack2(xa[2 * ks].x,     xa[2 * ks].y);
      t.u[1] = pack2(xa[2 * ks].z,     xa[2 * ks].w);
      t.u[2] = pack2(xa[2 * ks + 1].x, xa[2 * ks + 1].y);
      t.u[3] = pack2(xa[2 * ks + 1].z, xa[2 * ks + 1].w);
      bfX[ks] = t.s;
    }
    f32x4 acc[9];
#pragma unroll
    for (int i = 0; i < 9; ++i) acc[i] = (f32x4){0.f, 0.f, 0.f, 0.f};
#pragma unroll
    for (int ks = 0; ks < 3; ++ks) {
#pragma unroll
      for (int i = 0; i < 9; ++i) {
        const int mt = 2 * i + par;
        short8 afW = *(const short8*)&wqkv[(mt * 16 + lo4) * 96 + ks * 32 + hi4 * 8];
        acc[i] = __builtin_amdgcn_mfma_f32_16x16x32_bf16(afW, bfX[ks], acc[i], 0, 0, 0);
      }
    }
    // scatter: Q/K one b64 per tile (4 consecutive chans), V 4 scalar (chan-major)
#pragma unroll
    for (int i = 0; i < 9; ++i) {
      const int mt = 2 * i + par;
      const int o0 = mt * 16 + hi4 * 4;        // quad base out-channel (mult of 4)
      if (o0 < 192) {
        const int sec = (o0 >= 96) ? 96 : 0;
        const int o = o0 - sec;
        const int head = o / 12, ch = o - head * 12;   // ch in {0,4,8}
        uint2 w2;
        w2.x = pack2(acc[i][0], acc[i][1]);
        w2.y = pack2(acc[i][2], acc[i][3]);
        if (sec == 0) *(uint2*)&q_s[head][trow][ch] = w2;
        else          *(uint2*)&k_s[head][trow][ch] = w2;
      } else {
        const int o = o0 - 192;
        const int head = o / 12, ch = o - head * 12;
#pragma unroll
        for (int j = 0; j < 4; ++j)
          v_s[head][ch + j][trow] = f2bf(acc[i][j]);
      }
    }
  }

  // --- bias+mask c-init: 16 independent float4 loads issued BEFORE the
  //     barrier so their latency drains under the barrier wait ---
  f32x16 c[2][2];
  {
    const float* bm = biasm + (size_t)(wmask * 8 + wv) * 4096;
#pragma unroll
    for (int ti = 0; ti < 2; ++ti)
#pragma unroll
      for (int tj = 0; tj < 2; ++tj)
#pragma unroll
        for (int q4 = 0; q4 < 4; ++q4) {
          float4 b4 = *(const float4*)&bm[(tj * 32 + lo5) * 64 + ti * 32 + 8 * q4 + 4 * hi5];
          c[ti][tj][4 * q4 + 0] = b4.x;
          c[ti][tj][4 * q4 + 1] = b4.y;
          c[ti][tj][4 * q4 + 2] = b4.z;
          c[ti][tj][4 * q4 + 3] = b4.w;
        }
  }
  __syncthreads();

  // --- attention: wave wv handles head wv (S^T and softmax in exp2 domain) ---
  f32x16 oD[2];
  {
    const int h = wv;
#pragma unroll
    for (int ti = 0; ti < 2; ++ti) {
      short8 af = *(const short8*)&k_s[h][ti * 32 + lo5][hi5 * 8];
#pragma unroll
      for (int tj = 0; tj < 2; ++tj) {
        short8 bf = *(const short8*)&q_s[h][tj * 32 + lo5][hi5 * 8];
        c[ti][tj] = __builtin_amdgcn_mfma_f32_32x32x16_bf16(af, bf, c[ti][tj], 0, 0, 0);
      }
    }

    // softmax over m (rows of S^T): lane holds 32 of 64 m per q; partner lane^32
#pragma unroll
    for (int tj = 0; tj < 2; ++tj) {
      float mx = -1e30f;
#pragma unroll
      for (int ti = 0; ti < 2; ++ti)
#pragma unroll
        for (int reg = 0; reg < 16; ++reg) mx = fmaxf(mx, c[ti][tj][reg]);
      mx = fmaxf(mx, __shfl_xor(mx, 32));
      float sum = 0.f;
#pragma unroll
      for (int ti = 0; ti < 2; ++ti)
#pragma unroll
        for (int reg = 0; reg < 16; ++reg) {
          float e = exp2f(c[ti][tj][reg] - mx);
          c[ti][tj][reg] = e;
          sum += e;
        }
      sum += __shfl_xor(sum, 32);
      float rs = 1.0f / sum;
#pragma unroll
      for (int ti = 0; ti < 2; ++ti)
#pragma unroll
        for (int reg = 0; reg < 16; ++reg) c[ti][tj][reg] *= rs;
    }

    // pack P^T to bf16 pairs: pkp[ti][tj][u] = {reg 2u, reg 2u+1}
    uint32_t pkp[2][2][8];
#pragma unroll
    for (int ti = 0; ti < 2; ++ti)
#pragma unroll
      for (int tj = 0; tj < 2; ++tj)
#pragma unroll
        for (int u = 0; u < 8; ++u)
          pkp[ti][tj][u] = pack2(c[ti][tj][2 * u], c[ti][tj][2 * u + 1]);

    // PV: O^T = V^T @ P^T via 32x32x16. A = V^T from v_s (rows >= 12 garbage,
    // contained per-row, discarded). B = P^T assembled in-register:
    // needed m = 16*kc + 8*hi5 + 4*jh + r2 ; jh==hi5 -> own quad, else lane^32.
    oD[0] = (f32x16)(0.f); oD[1] = (f32x16)(0.f);
#pragma unroll
    for (int kc = 0; kc < 4; ++kc) {
      const int ti = kc >> 1, base = 4 * (kc & 1);
      short8 av = *(const short8*)&v_s[h][lo5 & 15][kc * 16 + hi5 * 8];
#pragma unroll
      for (int tj = 0; tj < 2; ++tj) {
        uint32_t A0 = pkp[ti][tj][base + 0], A1 = pkp[ti][tj][base + 1];
        uint32_t A2 = pkp[ti][tj][base + 2], A3 = pkp[ti][tj][base + 3];
        uint32_t k0 = hi5 ? A2 : A0, k1 = hi5 ? A3 : A1;
        uint32_t s0 = (uint32_t)__shfl_xor((int)(hi5 ? A0 : A2), 32);
        uint32_t s1 = (uint32_t)__shfl_xor((int)(hi5 ? A1 : A3), 32);
        union { uint32_t u[4]; short8 s; } bfr;
        bfr.u[0] = hi5 ? s0 : k0;
        bfr.u[1] = hi5 ? s1 : k1;
        bfr.u[2] = hi5 ? k0 : s0;
        bfr.u[3] = hi5 ? k1 : s1;
        oD[tj] = __builtin_amdgcn_mfma_f32_32x32x16_bf16(av, bfr.s, oD[tj], 0, 0, 0);
      }
    }
  }
  __syncthreads();   // all v_s reads done -> safe to overlay O

  // --- O^T[c][q] -> o_s[q][ch] (overlay on v_s), packed b64 ---
  {
    const int h = wv;
#pragma unroll
    for (int tj = 0; tj < 2; ++tj) {
      const int q = tj * 32 + lo5;
      uint2 w2;
      w2.x = pack2(oD[tj][0], oD[tj][1]);          // ch 4*hi5 + 0,1
      w2.y = pack2(oD[tj][2], oD[tj][3]);          // ch 4*hi5 + 2,3
      *(uint2*)&o_s[q][h * 12 + 4 * hi5] = w2;
      if (hi5 == 0) {
        uint2 w3;
        w3.x = pack2(oD[tj][4], oD[tj][5]);        // ch 8,9
        w3.y = pack2(oD[tj][6], oD[tj][7]);        // ch 10,11
        *(uint2*)&o_s[q][h * 12 + 8] = w3;
      }
    }
  }
  __syncthreads();

  // --- GEMM3: OUT = O @ Wproj^T + b (M=64 N=96 K=96); wave = (M-tile, 3 N-tiles) ---
  {
    const int mt = wv >> 1;           // M-tile 0..3
    const int nb = (wv & 1) * 3;      // first N-tile (0 or 3)
    f32x4 acc[3];
#pragma unroll
    for (int nt = 0; nt < 3; ++nt) acc[nt] = (f32x4){0.f, 0.f, 0.f, 0.f};
    const int arow = mt * 16 + lo4;
#pragma unroll
    for (int ks = 0; ks < 3; ++ks) {
      short8 af = *(const short8*)&o_s[arow][ks * 32 + hi4 * 8];
#pragma unroll
      for (int nt = 0; nt < 3; ++nt) {
        const int ntg = nb + nt;
        short8 bf = *(const short8*)&wproj[(ntg * 16 + lo4) * 96 + ks * 32 + hi4 * 8];
        acc[nt] = __builtin_amdgcn_mfma_f32_16x16x32_bf16(af, bf, acc[nt], 0, 0, 0);
      }
    }
    float* od = out + (size_t)blk * (64 * 96);
#pragma unroll
    for (int nt = 0; nt < 3; ++nt) {
      const int ntg = nb + nt;
      float pb = proj_b[ntg * 16 + lo4];
#pragma unroll
      for (int j = 0; j < 4; ++j)
        od[(mt * 16 + hi4 * 4 + j) * 96 + ntg * 16 + lo4] = acc[nt][j] + pb;
    }
  }
}

extern "C" void kernel_launch(void* const* d_in, const int* in_sizes, int n_in,
                              void* d_out, int out_size, void* d_ws, size_t ws_size,
                              hipStream_t stream) {
  const float* x          = (const float*)d_in[0];
  const float* mask       = (const float*)d_in[1];
  const float* qkv_w      = (const float*)d_in[2];
  const float* proj_w     = (const float*)d_in[3];
  const float* proj_b     = (const float*)d_in[4];
  const float* bias_table = (const float*)d_in[5];

  float* biasm = (float*)d_ws;
  unsigned short* ws16 = (unsigned short*)d_ws;

  prep_weights<<<144, 256, 0, stream>>>(qkv_w, proj_w, ws16);
  prep_biasm<<<8192, 256, 0, stream>>>(mask, bias_table, biasm);
  attn_main<<<4096, 512, 0, stream>>>(x, proj_b, ws16, biasm, (float*)d_out);
}

// Round 6
// 176.959 us; speedup vs baseline: 1.0759x; 1.0759x over previous
//
#include <hip/hip_runtime.h>
#include <hip/hip_bf16.h>
#include <stdint.h>

// Swin-3D window attention, fused. B=4096 windows, N=64 tokens, C=96, H=8, hd=12.
// R6: spill fix (launch_bounds 512,4), O overlays q_s[h] (no barrier between PV
// and O-write -> 2 barriers total), GEMM3 = zero-padded K=128 vs wprojT[8][96][16].
// 512 thr / 8 waves, one head per wave, LDS 51200 B.
//
// ws layout (bytes):
//   [0, 8388608)            biasm fp32 [64 w][8 h][64 q][64 m]  ((bias+mask)*log2e)
//   [8388608, +55296)       wqkv  bf16 [288][96]  (Q rows pre-scaled by hd^-0.5*log2e)
//   [8443904, +24576)       wprojT bf16 [8 h][96 o][16 c]  (chans 12..15 zero)

typedef float  f32x4  __attribute__((ext_vector_type(4)));
typedef float  f32x16 __attribute__((ext_vector_type(16)));
typedef short  short8 __attribute__((ext_vector_type(8)));

#define WS_WQKV_OFF   (8388608)
#define WS_WPROJT_OFF (8388608 + 55296)
#define LOG2E 1.4426950408889634f

__device__ __forceinline__ unsigned short f2bf(float f) {
  __hip_bfloat16 h = __float2bfloat16(f);
  return *reinterpret_cast<unsigned short*>(&h);
}
__device__ __forceinline__ uint32_t pack2(float a, float b) {
  __hip_bfloat162 h = __float22bfloat162_rn(float2{a, b});
  return *reinterpret_cast<uint32_t*>(&h);
}

__global__ void prep_weights(const float* __restrict__ qkv_w,
                             const float* __restrict__ proj_w,
                             unsigned short* __restrict__ ws16) {
  int tid = blockIdx.x * 256 + threadIdx.x;          // 156 blocks * 256 = 39936 exact
  if (tid < 27648) {
    float v = qkv_w[tid];
    if (tid < 9216) v *= (0.28867513459481288f * LOG2E);  // SCALE*log2e into Q rows
    ws16[WS_WQKV_OFF / 2 + tid] = f2bf(v);
  } else {
    int t = tid - 27648;                             // < 12288 = 8*96*16
    int h = t / 1536, rem = t - h * 1536;
    int o = rem >> 4, c = rem & 15;
    float v = (c < 12) ? proj_w[o * 96 + h * 12 + c] : 0.f;
    ws16[WS_WPROJT_OFF / 2 + t] = f2bf(v);
  }
}

// biasm[w][h][q=r][key=m] = (bias_table[relidx(r,m)][h] + mask[w][r][m]) * log2e
__global__ void prep_biasm(const float* __restrict__ mask,
                           const float* __restrict__ bias_table,
                           float* __restrict__ biasm) {
  int tid = blockIdx.x * 256 + threadIdx.x;          // 8192 blocks * 256 = 2097152 exact
  int m = tid & 63;            // key (inner)
  int r = (tid >> 6) & 63;     // query
  int h = (tid >> 12) & 7;
  int w = tid >> 15;
  int dr = r >> 4, hr = (r >> 2) & 3, wr = r & 3;
  int dm = m >> 4, hm = (m >> 2) & 3, wm = m & 3;
  int idx = (dr - dm + 3) * 49 + (hr - hm + 3) * 7 + (wr - wm + 3);
  biasm[tid] = (bias_table[idx * 8 + h] + mask[(w * 64 + r) * 64 + m]) * LOG2E;
}

__global__ __launch_bounds__(512, 4) void attn_main(
    const float* __restrict__ x, const float* __restrict__ proj_b,
    const unsigned short* __restrict__ ws16, const float* __restrict__ biasm,
    float* __restrict__ out) {
  // 51200 B total LDS
  __shared__ __align__(16) unsigned short q_s[8][64][16];  // Q then O^T overlay (per head)
  __shared__ __align__(16) unsigned short k_s[8][64][16];
  __shared__ __align__(16) unsigned short v_s[8][16][72];  // chan-major

  const int tid  = threadIdx.x;
  const int wv   = tid >> 6;          // 0..7
  const int lane = tid & 63;
  const int lo4 = lane & 15, hi4 = lane >> 4;
  const int lo5 = lane & 31, hi5 = lane >> 5;
  const int blk = blockIdx.x;
  const int wmask = blk & 63;

  const unsigned short* wqkv   = ws16 + WS_WQKV_OFF / 2;
  const unsigned short* wprojT = ws16 + WS_WPROJT_OFF / 2;

  // --- issue X loads first (HBM latency overlaps zero-pad + weight loads) ---
  const int sub = wv & 3;           // token tile (16 tokens)
  const int par = wv >> 2;          // M-tile parity
  const int trow = sub * 16 + lo4;  // this lane's token
  const float* xrow = x + (size_t)blk * 6144 + (size_t)trow * 96;
  float4 xa[6];
#pragma unroll
  for (int ks = 0; ks < 3; ++ks) {
    xa[2 * ks]     = *(const float4*)&xrow[ks * 32 + hi4 * 8];
    xa[2 * ks + 1] = *(const float4*)&xrow[ks * 32 + hi4 * 8 + 4];
  }

  // --- zero pad chans 12..15 of q_s/k_s (512 threads -> one shot) ---
  {
    int h = tid >> 6, r = tid & 63;
    *(uint2*)&q_s[h][r][12] = make_uint2(0u, 0u);
    *(uint2*)&k_s[h][r][12] = make_uint2(0u, 0u);
  }

  // --- GEMM1 (transposed): QKV^T = Wqkv @ X^T. wave = (token-tile, parity) ---
  {
    short8 bfX[3];
#pragma unroll
    for (int ks = 0; ks < 3; ++ks) {
      union { uint32_t u[4]; short8 s; } t;
      t.u[0] = pack2(xa[2 * ks].x,     xa[2 * ks].y);
      t.u[1] = pack2(xa[2 * ks].z,     xa[2 * ks].w);
      t.u[2] = pack2(xa[2 * ks + 1].x, xa[2 * ks + 1].y);
      t.u[3] = pack2(xa[2 * ks + 1].z, xa[2 * ks + 1].w);
      bfX[ks] = t.s;
    }
    f32x4 acc[9];
#pragma unroll
    for (int i = 0; i < 9; ++i) acc[i] = (f32x4){0.f, 0.f, 0.f, 0.f};
#pragma unroll
    for (int ks = 0; ks < 3; ++ks) {
#pragma unroll
      for (int i = 0; i < 9; ++i) {
        const int mt = 2 * i + par;
        short8 afW = *(const short8*)&wqkv[(mt * 16 + lo4) * 96 + ks * 32 + hi4 * 8];
        acc[i] = __builtin_amdgcn_mfma_f32_16x16x32_bf16(afW, bfX[ks], acc[i], 0, 0, 0);
      }
    }
    // scatter: Q/K one b64 per tile (4 consecutive chans), V 4 scalar (chan-major)
#pragma unroll
    for (int i = 0; i < 9; ++i) {
      const int mt = 2 * i + par;
      const int o0 = mt * 16 + hi4 * 4;        // quad base out-channel (mult of 4)
      if (o0 < 192) {
        const int sec = (o0 >= 96) ? 96 : 0;
        const int o = o0 - sec;
        const int head = o / 12, ch = o - head * 12;   // ch in {0,4,8}
        uint2 w2;
        w2.x = pack2(acc[i][0], acc[i][1]);
        w2.y = pack2(acc[i][2], acc[i][3]);
        if (sec == 0) *(uint2*)&q_s[head][trow][ch] = w2;
        else          *(uint2*)&k_s[head][trow][ch] = w2;
      } else {
        const int o = o0 - 192;
        const int head = o / 12, ch = o - head * 12;
#pragma unroll
        for (int j = 0; j < 4; ++j)
          v_s[head][ch + j][trow] = f2bf(acc[i][j]);
      }
    }
  }

  // --- bias+mask c-init: 16 independent float4 loads issued BEFORE the
  //     barrier so their latency drains under the barrier wait ---
  f32x16 c[2][2];
  {
    const float* bm = biasm + (size_t)(wmask * 8 + wv) * 4096;
#pragma unroll
    for (int ti = 0; ti < 2; ++ti)
#pragma unroll
      for (int tj = 0; tj < 2; ++tj)
#pragma unroll
        for (int q4 = 0; q4 < 4; ++q4) {
          float4 b4 = *(const float4*)&bm[(tj * 32 + lo5) * 64 + ti * 32 + 8 * q4 + 4 * hi5];
          c[ti][tj][4 * q4 + 0] = b4.x;
          c[ti][tj][4 * q4 + 1] = b4.y;
          c[ti][tj][4 * q4 + 2] = b4.z;
          c[ti][tj][4 * q4 + 3] = b4.w;
        }
  }
  __syncthreads();   // barrier 1: q/k/v staged

  // --- attention: wave wv handles head wv (S^T and softmax in exp2 domain) ---
  f32x16 oD[2];
  {
    const int h = wv;
    __builtin_amdgcn_s_setprio(1);
#pragma unroll
    for (int ti = 0; ti < 2; ++ti) {
      short8 af = *(const short8*)&k_s[h][ti * 32 + lo5][hi5 * 8];
#pragma unroll
      for (int tj = 0; tj < 2; ++tj) {
        short8 bf = *(const short8*)&q_s[h][tj * 32 + lo5][hi5 * 8];
        c[ti][tj] = __builtin_amdgcn_mfma_f32_32x32x16_bf16(af, bf, c[ti][tj], 0, 0, 0);
      }
    }
    __builtin_amdgcn_s_setprio(0);

    // softmax over m (rows of S^T): lane holds 32 of 64 m per q; partner lane^32
#pragma unroll
    for (int tj = 0; tj < 2; ++tj) {
      float mx = -1e30f;
#pragma unroll
      for (int ti = 0; ti < 2; ++ti)
#pragma unroll
        for (int reg = 0; reg < 16; ++reg) mx = fmaxf(mx, c[ti][tj][reg]);
      mx = fmaxf(mx, __shfl_xor(mx, 32));
      float sum = 0.f;
#pragma unroll
      for (int ti = 0; ti < 2; ++ti)
#pragma unroll
        for (int reg = 0; reg < 16; ++reg) {
          float e = exp2f(c[ti][tj][reg] - mx);
          c[ti][tj][reg] = e;
          sum += e;
        }
      sum += __shfl_xor(sum, 32);
      float rs = 1.0f / sum;
#pragma unroll
      for (int ti = 0; ti < 2; ++ti)
#pragma unroll
        for (int reg = 0; reg < 16; ++reg) c[ti][tj][reg] *= rs;
    }

    // pack P^T to bf16 pairs: pkp[ti][tj][u] = {reg 2u, reg 2u+1}
    uint32_t pkp[2][2][8];
#pragma unroll
    for (int ti = 0; ti < 2; ++ti)
#pragma unroll
      for (int tj = 0; tj < 2; ++tj)
#pragma unroll
        for (int u = 0; u < 8; ++u)
          pkp[ti][tj][u] = pack2(c[ti][tj][2 * u], c[ti][tj][2 * u + 1]);

    // PV: O^T = V^T @ P^T via 32x32x16. A = V^T from v_s (rows >= 12 garbage,
    // contained per-row, discarded). B = P^T assembled in-register:
    // needed m = 16*kc + 8*hi5 + 4*jh + r2 ; jh==hi5 -> own quad, else lane^32.
    oD[0] = (f32x16)(0.f); oD[1] = (f32x16)(0.f);
#pragma unroll
    for (int kc = 0; kc < 4; ++kc) {
      const int ti = kc >> 1, base = 4 * (kc & 1);
      short8 av = *(const short8*)&v_s[h][lo5 & 15][kc * 16 + hi5 * 8];
#pragma unroll
      for (int tj = 0; tj < 2; ++tj) {
        uint32_t A0 = pkp[ti][tj][base + 0], A1 = pkp[ti][tj][base + 1];
        uint32_t A2 = pkp[ti][tj][base + 2], A3 = pkp[ti][tj][base + 3];
        uint32_t k0 = hi5 ? A2 : A0, k1 = hi5 ? A3 : A1;
        uint32_t s0 = (uint32_t)__shfl_xor((int)(hi5 ? A0 : A2), 32);
        uint32_t s1 = (uint32_t)__shfl_xor((int)(hi5 ? A1 : A3), 32);
        union { uint32_t u[4]; short8 s; } bfr;
        bfr.u[0] = hi5 ? s0 : k0;
        bfr.u[1] = hi5 ? s1 : k1;
        bfr.u[2] = hi5 ? k0 : s0;
        bfr.u[3] = hi5 ? k1 : s1;
        __builtin_amdgcn_s_setprio(1);
        oD[tj] = __builtin_amdgcn_mfma_f32_32x32x16_bf16(av, bfr.s, oD[tj], 0, 0, 0);
        __builtin_amdgcn_s_setprio(0);
      }
    }

    // O^T[c][q] -> overlay q_s[h][q][0..11] (own wave wrote+read q_s[h]; no sync
    // needed — DS ops are wave-ordered, and no other wave touches q_s[h])
#pragma unroll
    for (int tj = 0; tj < 2; ++tj) {
      const int q = tj * 32 + lo5;
      uint2 w2;
      w2.x = pack2(oD[tj][0], oD[tj][1]);          // ch 4*hi5 + 0,1
      w2.y = pack2(oD[tj][2], oD[tj][3]);          // ch 4*hi5 + 2,3
      *(uint2*)&q_s[h][q][4 * hi5] = w2;
      if (hi5 == 0) {
        uint2 w3;
        w3.x = pack2(oD[tj][4], oD[tj][5]);        // ch 8,9
        w3.y = pack2(oD[tj][6], oD[tj][7]);        // ch 10,11
        *(uint2*)&q_s[h][q][8] = w3;
      }
    }
  }
  __syncthreads();   // barrier 2: all heads' O in q_s

  // --- GEMM3: OUT = O @ Wproj^T + b, K=128 zero-padded (8 heads x 16 chans).
  //     A: q_s[head][tok][16]; B: wprojT[head][out][16]. 4 ksteps x 3 N-tiles. ---
  {
    const int mt = wv >> 1;           // M-tile 0..3
    const int nb = (wv & 1) * 3;      // first N-tile (0 or 3)
    const int arow = mt * 16 + lo4;
    const int hh   = hi4 >> 1;        // head offset within kstep pair
    const int off8 = (hi4 & 1) * 8;   // chan offset 0/8
    f32x4 acc[3];
#pragma unroll
    for (int nt = 0; nt < 3; ++nt) acc[nt] = (f32x4){0.f, 0.f, 0.f, 0.f};
#pragma unroll
    for (int ks = 0; ks < 4; ++ks) {
      const int hsel = ks * 2 + hh;
      short8 af = *(const short8*)&q_s[hsel][arow][off8];
#pragma unroll
      for (int nt = 0; nt < 3; ++nt) {
        const int ntg = nb + nt;
        short8 bf = *(const short8*)&wprojT[((size_t)hsel * 96 + ntg * 16 + lo4) * 16 + off8];
        acc[nt] = __builtin_amdgcn_mfma_f32_16x16x32_bf16(af, bf, acc[nt], 0, 0, 0);
      }
    }
    float* od = out + (size_t)blk * (64 * 96);
#pragma unroll
    for (int nt = 0; nt < 3; ++nt) {
      const int ntg = nb + nt;
      float pb = proj_b[ntg * 16 + lo4];
#pragma unroll
      for (int j = 0; j < 4; ++j)
        od[(mt * 16 + hi4 * 4 + j) * 96 + ntg * 16 + lo4] = acc[nt][j] + pb;
    }
  }
}

extern "C" void kernel_launch(void* const* d_in, const int* in_sizes, int n_in,
                              void* d_out, int out_size, void* d_ws, size_t ws_size,
                              hipStream_t stream) {
  const float* x          = (const float*)d_in[0];
  const float* mask       = (const float*)d_in[1];
  const float* qkv_w      = (const float*)d_in[2];
  const float* proj_w     = (const float*)d_in[3];
  const float* proj_b     = (const float*)d_in[4];
  const float* bias_table = (const float*)d_in[5];

  float* biasm = (float*)d_ws;
  unsigned short* ws16 = (unsigned short*)d_ws;

  prep_weights<<<156, 256, 0, stream>>>(qkv_w, proj_w, ws16);
  prep_biasm<<<8192, 256, 0, stream>>>(mask, bias_table, biasm);
  attn_main<<<4096, 512, 0, stream>>>(x, proj_b, ws16, biasm, (float*)d_out);
}